// Round 1
// baseline (3149.342 us; speedup 1.0000x reference)
//
#include <hip/hip_runtime.h>

typedef float f32x4v __attribute__((ext_vector_type(4)));
typedef short s16x8  __attribute__((ext_vector_type(8)));

#define MT 32  // batch rows per block

// instruction metadata: 11 paths (i1,i2,io); l == index for both irreps sets
constexpr int cI1[11]   = {0,0,0,1,1,1,1,2,2,2,2};
constexpr int cI2[11]   = {0,1,2,0,1,1,2,0,1,2,2};
constexpr int cIO[11]   = {0,1,2,1,0,2,1,2,1,0,2};
constexpr int cSOFF[11] = {0,1,4,9,18,21,36,45,70,85,90}; // cum of (2l1+1)(2lo+1), total 115
constexpr int cOFF1[3]  = {0,128,512};
constexpr int cOFF2[3]  = {0,1,4};

__device__ __forceinline__ unsigned short f2bf(float f){
  unsigned int u = __float_as_uint(f);
  u = u + 0x7fffu + ((u>>16)&1u);
  return (unsigned short)(u>>16);
}

// ===================== prep kernel 1: Wigner 3j (faithful port) =====================
__device__ double dfact(int n){ double r=1.0; for(int i=2;i<=n;++i) r*=(double)i; return r; }

__device__ double cg1(int j1,int m1,int j2,int m2,int j3,int m3){
  int vmin = -j1+j2+m3; int t=-j1+m1; if(t>vmin)vmin=t; if(vmin<0)vmin=0;
  int vmax = j2+j3+m1; t=j3-j1+j2; if(t<vmax)vmax=t; t=j3+m3; if(t<vmax)vmax=t;
  double C = sqrt((2.0*j3+1.0)*dfact(j3+j1-j2)*dfact(j3-j1+j2)*dfact(j1+j2-j3)
                 *dfact(j3+m3)*dfact(j3-m3)
                 /(dfact(j1+j2+j3+1)*dfact(j1-m1)*dfact(j1+m1)*dfact(j2-m2)*dfact(j2+m2)));
  double S=0.0;
  for(int v=vmin;v<=vmax;++v){
    double sg = ((v+j2+m2)&1)? -1.0:1.0;
    S += sg*dfact(j2+j3+m1-v)*dfact(j1-m1+v)
        /(dfact(v)*dfact(j3-j1+j2-v)*dfact(j3+m3-v)*dfact(v+j1-j2-m3));
  }
  return C*S;
}

__device__ void qmat(int l, double (&qr)[5][5], double (&qi)[5][5]){
  for(int a=0;a<5;a++)for(int b=0;b<5;b++){qr[a][b]=0.0;qi[a][b]=0.0;}
  const double s2=0.70710678118654752440;
  for(int m=-l;m<0;m++){ qr[l+m][l-m]=s2; qi[l+m][l+m]=-s2; }
  qr[l][l]=1.0;
  for(int m=1;m<=l;m++){ double sg=(m&1)?-1.0:1.0; qr[l+m][l+m]=sg*s2; qi[l+m][l-m]=sg*s2; }
  int ph=l&3; // multiply by (-i)^l
  if(ph){
    for(int a=0;a<5;a++)for(int b=0;b<5;b++){
      double r=qr[a][b], im=qi[a][b];
      if(ph==1){ qr[a][b]=im;  qi[a][b]=-r;  }
      else if(ph==2){ qr[a][b]=-r; qi[a][b]=-im; }
      else { qr[a][b]=-im; qi[a][b]=r; }
    }
  }
}

__global__ void prep_cg(float* __restrict__ wsC){
  int idx = threadIdx.x;
  if (idx >= 11) return;
  int l1=cI1[idx], l2=cI2[idx], l3=cIO[idx];
  int n1=2*l1+1,n2=2*l2+1,n3=2*l3+1;
  double cg[5][5][5];
  for(int a=0;a<5;a++)for(int b=0;b<5;b++)for(int c=0;c<5;c++)cg[a][b][c]=0.0;
  for(int m1=-l1;m1<=l1;m1++)for(int m2=-l2;m2<=l2;m2++){
    int m3=m1+m2;
    if(m3>=-l3 && m3<=l3) cg[l1+m1][l2+m2][l3+m3]=cg1(l1,m1,l2,m2,l3,m3);
  }
  double q1r[5][5],q1i[5][5],q2r[5][5],q2i[5][5],q3r[5][5],q3i[5][5];
  qmat(l1,q1r,q1i); qmat(l2,q2r,q2i); qmat(l3,q3r,q3i);
  double outv[5][5][5]; double nrm=0.0;
  for(int j=0;j<5;j++)for(int L=0;L<5;L++)for(int m=0;m<5;m++)outv[j][L][m]=0.0;
  for(int j=0;j<n1;j++)for(int L=0;L<n2;L++)for(int m=0;m<n3;m++){
    double acc=0.0;
    for(int i=0;i<n1;i++)for(int k=0;k<n2;k++){
      double ar=q1r[i][j], ai=q1i[i][j];
      double br=q2r[k][L], bi=q2i[k][L];
      double pr=ar*br-ai*bi, pi=ar*bi+ai*br;
      for(int n=0;n<n3;n++){
        double c=cg[i][k][n];
        if(c!=0.0) acc += c*(pr*q3r[n][m] + pi*q3i[n][m]); // * conj(q3[n][m]), real part
      }
    }
    outv[j][L][m]=acc; nrm+=acc*acc;
  }
  double inv=1.0/sqrt(nrm);
  for(int j=0;j<5;j++)for(int L=0;L<5;L++)for(int m=0;m<5;m++)
    wsC[idx*125 + j*25 + L*5 + m] = (float)(outv[j][L][m]*inv);
}

// ===================== prep kernel 2: pack W' = w1*w2*pathw as bf16 B-frags =====================
__global__ void prep_w(const float* __restrict__ w1, const float* __restrict__ w2,
                       unsigned char* __restrict__ wsB){
  int gid = blockIdx.x*256 + threadIdx.x;
  if (gid >= 11*8*4*64) return;
  int lane = gid & 63;
  int g = gid >> 6;           // 0..351
  int kst = g & 3, nt = (g>>2)&7, idx = g>>5;
  int io = cIO[idx];
  float pw = (io==0)?0.051031036307982884f:((io==1)?0.07654655446197431f:0.09882117688026186f);
  int u0 = kst*32 + ((lane>>4)&3)*8;
  int w  = nt*16 + (lane&15);
  float w2v = w2[idx*128 + w] * pw;
  s16x8 p;
  #pragma unroll
  for (int e=0;e<8;e++){
    float v = w1[idx*16384 + (u0+e)*128 + w] * w2v;
    p[e] = (short)f2bf(v);
  }
  *(s16x8*)(wsB + (size_t)g*1024 + (size_t)lane*16) = p;
}

// ===================== main kernel =====================
template<int IDX, int NK>
__device__ __forceinline__ void do_idx(f32x4v (&acc)[NK][2],
    const float* __restrict__ x1, const unsigned char* __restrict__ wsB,
    unsigned char* lds, const float* s_lds, int brow0, int tid){
  constexpr int I1 = cI1[IDX];
  constexpr int NI = 2*I1+1;
  const int lane = tid & 63, wave = tid >> 6;
  const int mtile = wave >> 2, ng0 = (wave & 3)*2;
  // B fragments from global (frag-linear layout, L2-resident)
  s16x8 bfr[2][4];
  #pragma unroll
  for(int nt=0;nt<2;nt++)
    #pragma unroll
    for(int kst=0;kst<4;kst++)
      bfr[nt][kst] = *(const s16x8*)(wsB + (size_t)(((IDX*8 + ng0+nt)*4 + kst)*64 + lane)*16);
  const int tb = tid >> 4, tu0 = (tid & 15)*8;
  const float* xrow = x1 + (size_t)(brow0+tb)*1152 + cOFF1[I1] + tu0*NI;
  const int row = mtile*16 + (lane&15);
  const int rsw = (row&7)<<4;
  const int hi  = (lane>>4)&3;
  #pragma unroll
  for(int kc0=0;kc0<NK;kc0+=3){
    __syncthreads();                 // previous T consumers done
    f32x4v xv[2*NI];
    #pragma unroll
    for(int f=0;f<2*NI;f++) xv[f] = ((const f32x4v*)xrow)[f];
    #pragma unroll
    for(int kk=0;kk<3;kk++) if(kc0+kk<NK){
      const int k=kc0+kk;
      float sv[NI];
      #pragma unroll
      for(int i=0;i<NI;i++) sv[i]=s_lds[tb*116 + cSOFF[IDX] + i*NK + k];
      s16x8 tp;
      #pragma unroll
      for(int u=0;u<8;u++){
        float tvv=0.0f;
        #pragma unroll
        for(int i=0;i<NI;i++){ const int n=u*NI+i; tvv += sv[i]*xv[n>>2][n&3]; }
        tp[u]=(short)f2bf(tvv);
      }
      *(s16x8*)(lds + kk*8192 + tb*256 + ((tu0*2) ^ ((tb&7)<<4))) = tp;
    }
    __syncthreads();                 // T ready
    #pragma unroll
    for(int kk=0;kk<3;kk++) if(kc0+kk<NK){
      #pragma unroll
      for(int kst=0;kst<4;kst++){
        s16x8 af = *(const s16x8*)(lds + kk*8192 + row*256 + ((kst*64 + hi*16) ^ rsw));
        #pragma unroll
        for(int nt=0;nt<2;nt++)
          acc[kc0+kk][nt] = __builtin_amdgcn_mfma_f32_16x16x32_bf16(af, bfr[nt][kst], acc[kc0+kk][nt], 0,0,0);
      }
    }
  }
}

template<int OO, int NK>
__device__ __forceinline__ void store_group(f32x4v (&acc)[NK][2], float* __restrict__ out, int brow0, int tid){
  const int lane=tid&63, wave=tid>>6;
  const int mtile=wave>>2, ng0=(wave&3)*2;
  const int r0 = brow0 + mtile*16 + ((lane>>4)&3)*4;
  #pragma unroll
  for(int nt=0;nt<2;nt++){
    const int w = (ng0+nt)*16 + (lane&15);
    #pragma unroll
    for(int k=0;k<NK;k++){
      #pragma unroll
      for(int rr=0;rr<4;rr++)
        out[(size_t)(r0+rr)*1152 + OO + w*NK + k] = acc[k][nt][rr];
    }
  }
}

__global__ __launch_bounds__(512) void tp_main(
    const float* __restrict__ x1, const float* __restrict__ x2,
    const float* __restrict__ wsC, const unsigned char* __restrict__ wsB,
    float* __restrict__ out){
  __shared__ __attribute__((aligned(16))) unsigned char lds[24576 + 32*116*4];
  float* s_lds = (float*)(lds + 24576);
  const int tid = threadIdx.x;
  const int brow0 = blockIdx.x * MT;
  // s-table: s[b][(idx,i,k)] = sum_j C_idx[i,j,k] * x2[b, off2+j]
  if (tid < 352){
    const int b = tid & 31, idx = tid >> 5;
    const int i1=cI1[idx], i2=cI2[idx], io=cIO[idx];
    const int ni=2*i1+1, nj=2*i2+1, nk=2*io+1;
    const float* x2r = x2 + (size_t)(brow0+b)*9 + cOFF2[i2];
    const float* C = wsC + idx*125;
    float xv[5];
    for(int j=0;j<nj;j++) xv[j]=x2r[j];
    for(int i=0;i<ni;i++)
      for(int k=0;k<nk;k++){
        float s=0.f;
        for(int j=0;j<nj;j++) s += C[i*25+j*5+k]*xv[j];
        s_lds[b*116 + cSOFF[idx] + i*nk + k] = s;
      }
  }
  // io = 0 (lo=0), paths {0,4,9}
  {
    f32x4v acc[1][2] = {};
    do_idx<0,1>(acc,x1,wsB,lds,s_lds,brow0,tid);
    do_idx<4,1>(acc,x1,wsB,lds,s_lds,brow0,tid);
    do_idx<9,1>(acc,x1,wsB,lds,s_lds,brow0,tid);
    store_group<0,1>(acc,out,brow0,tid);
  }
  // io = 1 (lo=1), paths {1,3,6,8}
  {
    f32x4v acc[3][2] = {};
    do_idx<1,3>(acc,x1,wsB,lds,s_lds,brow0,tid);
    do_idx<3,3>(acc,x1,wsB,lds,s_lds,brow0,tid);
    do_idx<6,3>(acc,x1,wsB,lds,s_lds,brow0,tid);
    do_idx<8,3>(acc,x1,wsB,lds,s_lds,brow0,tid);
    store_group<128,3>(acc,out,brow0,tid);
  }
  // io = 2 (lo=2), paths {2,5,7,10}
  {
    f32x4v acc[5][2] = {};
    do_idx<2,5>(acc,x1,wsB,lds,s_lds,brow0,tid);
    do_idx<5,5>(acc,x1,wsB,lds,s_lds,brow0,tid);
    do_idx<7,5>(acc,x1,wsB,lds,s_lds,brow0,tid);
    do_idx<10,5>(acc,x1,wsB,lds,s_lds,brow0,tid);
    store_group<512,5>(acc,out,brow0,tid);
  }
}

extern "C" void kernel_launch(void* const* d_in, const int* in_sizes, int n_in,
                              void* d_out, int out_size, void* d_ws, size_t ws_size,
                              hipStream_t stream) {
  const float* x1 = (const float*)d_in[0];
  const float* x2 = (const float*)d_in[1];
  const float* w1 = (const float*)d_in[2];
  const float* w2 = (const float*)d_in[3];
  float* out = (float*)d_out;
  float* wsC = (float*)d_ws;                          // 11*125 floats (CG tensors)
  unsigned char* wsB = (unsigned char*)d_ws + 8192;   // 352 KiB packed bf16 weights
  prep_cg<<<1, 64, 0, stream>>>(wsC);
  prep_w<<<88, 256, 0, stream>>>(w1, w2, wsB);
  tp_main<<<32768/MT, 512, 0, stream>>>(x1, x2, wsC, wsB, out);
}

// Round 10
// 408.855 us; speedup vs baseline: 7.7028x; 7.7028x over previous
//
#include <hip/hip_runtime.h>

typedef float f32x4v __attribute__((ext_vector_type(4)));
typedef short s16x8  __attribute__((ext_vector_type(8)));

#define MT 32  // batch rows per block

// instruction metadata: 11 paths (i1,i2,io); l == index for both irreps sets
constexpr int cI1[11]   = {0,0,0,1,1,1,1,2,2,2,2};
constexpr int cI2[11]   = {0,1,2,0,1,1,2,0,1,2,2};
constexpr int cIO[11]   = {0,1,2,1,0,2,1,2,1,0,2};
constexpr int cSOFF[11] = {0,1,4,9,18,21,36,45,70,85,90}; // cum of (2l1+1)(2lo+1), total 115
constexpr int cOFF1[3]  = {0,128,512};
constexpr int cOFF2[3]  = {0,1,4};

__device__ __forceinline__ unsigned short f2bf(float f){
  unsigned int u = __float_as_uint(f);
  u = u + 0x7fffu + ((u>>16)&1u);
  return (unsigned short)(u>>16);
}

// ===================== prep kernel 1: Wigner 3j (parallel, LDS-resident, fp32) =====================
__device__ __forceinline__ float ffact(int n){ float r=1.f; for(int i=2;i<=n;++i) r*=(float)i; return r; }

__device__ float cg1f(int j1,int m1,int j2,int m2,int j3,int m3){
  int vmin = -j1+j2+m3; int t=-j1+m1; if(t>vmin)vmin=t; if(vmin<0)vmin=0;
  int vmax = j2+j3+m1; t=j3-j1+j2; if(t<vmax)vmax=t; t=j3+m3; if(t<vmax)vmax=t;
  float C = sqrtf((2.f*j3+1.f)*ffact(j3+j1-j2)*ffact(j3-j1+j2)*ffact(j1+j2-j3)
                 *ffact(j3+m3)*ffact(j3-m3)
                 /(ffact(j1+j2+j3+1)*ffact(j1-m1)*ffact(j1+m1)*ffact(j2-m2)*ffact(j2+m2)));
  float S=0.f;
  for(int v=vmin;v<=vmax;++v){
    float sg = ((v+j2+m2)&1)? -1.f:1.f;
    S += sg*ffact(j2+j3+m1-v)*ffact(j1-m1+v)
        /(ffact(v)*ffact(j3-j1+j2-v)*ffact(j3+m3-v)*ffact(v+j1-j2-m3));
  }
  return C*S;
}

__global__ void prep_cg(float* __restrict__ wsC){
  __shared__ float s_cg[125];
  __shared__ float s_qr[3][25], s_qi[3][25];
  __shared__ float s_out[125];
  __shared__ float s_inv;
  const int idx = blockIdx.x;
  const int l1=cI1[idx], l2=cI2[idx], l3=cIO[idx];
  const int n1=2*l1+1, n2=2*l2+1, n3=2*l3+1;
  const int tid = threadIdx.x;
  if (tid < 125) s_cg[tid] = 0.f;
  __syncthreads();
  // q matrices: one thread per (mat, a, b) element
  if (tid < 75){
    const int mat=tid/25, e=tid%25, a=e/5, b=e%5;
    const int l = (mat==0)?l1:((mat==1)?l2:l3);
    const int n = 2*l+1;
    float r=0.f, im=0.f;
    if (a<n && b<n){
      const int m = a - l;
      const float s2 = 0.70710678118654752440f;
      if (m < 0){
        if (b == l-m) r = s2;            // col l+|m|
        else if (b == a) im = -s2;       // col l-|m| == a
      } else if (m == 0){
        if (b == a) r = 1.f;
      } else {
        const float sg = (m&1)? -1.f:1.f;
        if (b == a) r = sg*s2;           // col l+m == a
        else if (b == l-m) im = sg*s2;   // col l-m
      }
      const int ph = l & 3;              // multiply by (-i)^l
      if (ph == 1){ float t=r; r=im; im=-t; }
      else if (ph == 2){ r=-r; im=-im; }
      else if (ph == 3){ float t=r; r=-im; im=t; }
    }
    s_qr[mat][e] = r; s_qi[mat][e] = im;
  }
  // CG table: one thread per (m1,m2)
  if (tid < n1*n2){
    const int m1 = tid / n2 - l1;
    const int m2 = tid % n2 - l2;
    const int m3 = m1 + m2;
    if (m3 >= -l3 && m3 <= l3)
      s_cg[(l1+m1)*25 + (l2+m2)*5 + (l3+m3)] = cg1f(l1,m1,l2,m2,l3,m3);
  }
  __syncthreads();
  // contraction: one thread per (j,L,m) valid output element (compact index)
  const int nElem = n1*n2*n3;
  if (tid < nElem){
    const int j = tid/(n2*n3);
    const int L = (tid/n3) % n2;
    const int m = tid % n3;
    float acc = 0.f;
    for (int i=0;i<n1;i++){
      const float ar=s_qr[0][i*5+j], ai=s_qi[0][i*5+j];
      for (int k=0;k<n2;k++){
        const float br=s_qr[1][k*5+L], bi=s_qi[1][k*5+L];
        const float pr=ar*br-ai*bi, pi=ar*bi+ai*br;
        for (int n=0;n<n3;n++){
          const float c=s_cg[i*25+k*5+n];
          acc += c*(pr*s_qr[2][n*5+m] + pi*s_qi[2][n*5+m]); // * conj(q3[n][m]), real part
        }
      }
    }
    s_out[tid] = acc;
  }
  __syncthreads();
  if (tid == 0){
    float nrm = 0.f;
    for (int t=0;t<nElem;t++) nrm += s_out[t]*s_out[t];
    s_inv = rsqrtf(nrm);
  }
  __syncthreads();
  // scatter to full 5x5x5 layout with zero fill
  if (tid < 125){
    const int j=tid/25, L=(tid/5)%5, m=tid%5;
    float v = 0.f;
    if (j<n1 && L<n2 && m<n3) v = s_out[(j*n2+L)*n3+m] * s_inv;
    wsC[idx*125 + tid] = v;
  }
}

// ===================== prep kernel 2: pack W' = w1*w2*pathw as bf16 B-frags =====================
__global__ void prep_w(const float* __restrict__ w1, const float* __restrict__ w2,
                       unsigned char* __restrict__ wsB){
  int gid = blockIdx.x*256 + threadIdx.x;
  if (gid >= 11*8*4*64) return;
  int lane = gid & 63;
  int g = gid >> 6;           // 0..351
  int kst = g & 3, nt = (g>>2)&7, idx = g>>5;
  int io = cIO[idx];
  float pw = (io==0)?0.051031036307982884f:((io==1)?0.07654655446197431f:0.09882117688026186f);
  int u0 = kst*32 + ((lane>>4)&3)*8;
  int w  = nt*16 + (lane&15);
  float w2v = w2[idx*128 + w] * pw;
  s16x8 p;
  #pragma unroll
  for (int e=0;e<8;e++){
    float v = w1[idx*16384 + (u0+e)*128 + w] * w2v;
    p[e] = (short)f2bf(v);
  }
  *(s16x8*)(wsB + (size_t)g*1024 + (size_t)lane*16) = p;
}

// ===================== main kernel =====================
template<int IDX, int NK>
__device__ __forceinline__ void do_idx(f32x4v (&acc)[NK][2],
    const float* __restrict__ x1, const unsigned char* __restrict__ wsB,
    unsigned char* lds, const float* s_lds, int brow0, int tid){
  constexpr int I1 = cI1[IDX];
  constexpr int NI = 2*I1+1;
  const int lane = tid & 63, wave = tid >> 6;
  const int mtile = wave >> 2, ng0 = (wave & 3)*2;
  // B fragments from global (frag-linear layout, L2-resident)
  s16x8 bfr[2][4];
  #pragma unroll
  for(int nt=0;nt<2;nt++)
    #pragma unroll
    for(int kst=0;kst<4;kst++)
      bfr[nt][kst] = *(const s16x8*)(wsB + (size_t)(((IDX*8 + ng0+nt)*4 + kst)*64 + lane)*16);
  const int tb = tid >> 4, tu0 = (tid & 15)*8;
  const float* xrow = x1 + (size_t)(brow0+tb)*1152 + cOFF1[I1] + tu0*NI;
  const int row = mtile*16 + (lane&15);
  const int rsw = (row&7)<<4;
  const int hi  = (lane>>4)&3;
  // hoisted x1 segment load: loop-invariant, and the compiler can't hoist it
  // across __syncthreads() itself (barrier = memory clobber)
  f32x4v xv[2*NI];
  #pragma unroll
  for(int f=0;f<2*NI;f++) xv[f] = ((const f32x4v*)xrow)[f];
  #pragma unroll
  for(int kc0=0;kc0<NK;kc0+=3){
    __syncthreads();                 // previous T consumers done
    #pragma unroll
    for(int kk=0;kk<3;kk++) if(kc0+kk<NK){
      const int k=kc0+kk;
      float sv[NI];
      #pragma unroll
      for(int i=0;i<NI;i++) sv[i]=s_lds[tb*116 + cSOFF[IDX] + i*NK + k];
      s16x8 tp;
      #pragma unroll
      for(int u=0;u<8;u++){
        float tvv=0.0f;
        #pragma unroll
        for(int i=0;i<NI;i++){ const int n=u*NI+i; tvv += sv[i]*xv[n>>2][n&3]; }
        tp[u]=(short)f2bf(tvv);
      }
      *(s16x8*)(lds + kk*8192 + tb*256 + ((tu0*2) ^ ((tb&7)<<4))) = tp;
    }
    __syncthreads();                 // T ready
    #pragma unroll
    for(int kk=0;kk<3;kk++) if(kc0+kk<NK){
      #pragma unroll
      for(int kst=0;kst<4;kst++){
        s16x8 af = *(const s16x8*)(lds + kk*8192 + row*256 + ((kst*64 + hi*16) ^ rsw));
        #pragma unroll
        for(int nt=0;nt<2;nt++)
          acc[kc0+kk][nt] = __builtin_amdgcn_mfma_f32_16x16x32_bf16(af, bfr[nt][kst], acc[kc0+kk][nt], 0,0,0);
      }
    }
  }
}

template<int OO, int NK>
__device__ __forceinline__ void store_group(f32x4v (&acc)[NK][2], float* __restrict__ out, int brow0, int tid){
  const int lane=tid&63, wave=tid>>6;
  const int mtile=wave>>2, ng0=(wave&3)*2;
  const int r0 = brow0 + mtile*16 + ((lane>>4)&3)*4;
  #pragma unroll
  for(int nt=0;nt<2;nt++){
    const int w = (ng0+nt)*16 + (lane&15);
    #pragma unroll
    for(int k=0;k<NK;k++){
      #pragma unroll
      for(int rr=0;rr<4;rr++)
        out[(size_t)(r0+rr)*1152 + OO + w*NK + k] = acc[k][nt][rr];
    }
  }
}

__global__ __launch_bounds__(512) void tp_main(
    const float* __restrict__ x1, const float* __restrict__ x2,
    const float* __restrict__ wsC, const unsigned char* __restrict__ wsB,
    float* __restrict__ out){
  __shared__ __attribute__((aligned(16))) unsigned char lds[24576 + 32*116*4];
  float* s_lds = (float*)(lds + 24576);
  const int tid = threadIdx.x;
  const int brow0 = blockIdx.x * MT;
  // s-table: s[b][(idx,i,k)] = sum_j C_idx[i,j,k] * x2[b, off2+j]
  if (tid < 352){
    const int b = tid & 31, idx = tid >> 5;
    const int i1=cI1[idx], i2=cI2[idx], io=cIO[idx];
    const int ni=2*i1+1, nj=2*i2+1, nk=2*io+1;
    const float* x2r = x2 + (size_t)(brow0+b)*9 + cOFF2[i2];
    const float* C = wsC + idx*125;
    float xv[5];
    for(int j=0;j<nj;j++) xv[j]=x2r[j];
    for(int i=0;i<ni;i++)
      for(int k=0;k<nk;k++){
        float s=0.f;
        for(int j=0;j<nj;j++) s += C[i*25+j*5+k]*xv[j];
        s_lds[b*116 + cSOFF[idx] + i*nk + k] = s;
      }
  }
  // io = 0 (lo=0), paths {0,4,9}
  {
    f32x4v acc[1][2] = {};
    do_idx<0,1>(acc,x1,wsB,lds,s_lds,brow0,tid);
    do_idx<4,1>(acc,x1,wsB,lds,s_lds,brow0,tid);
    do_idx<9,1>(acc,x1,wsB,lds,s_lds,brow0,tid);
    store_group<0,1>(acc,out,brow0,tid);
  }
  // io = 1 (lo=1), paths {1,3,6,8}
  {
    f32x4v acc[3][2] = {};
    do_idx<1,3>(acc,x1,wsB,lds,s_lds,brow0,tid);
    do_idx<3,3>(acc,x1,wsB,lds,s_lds,brow0,tid);
    do_idx<6,3>(acc,x1,wsB,lds,s_lds,brow0,tid);
    do_idx<8,3>(acc,x1,wsB,lds,s_lds,brow0,tid);
    store_group<128,3>(acc,out,brow0,tid);
  }
  // io = 2 (lo=2), paths {2,5,7,10}
  {
    f32x4v acc[5][2] = {};
    do_idx<2,5>(acc,x1,wsB,lds,s_lds,brow0,tid);
    do_idx<5,5>(acc,x1,wsB,lds,s_lds,brow0,tid);
    do_idx<7,5>(acc,x1,wsB,lds,s_lds,brow0,tid);
    do_idx<10,5>(acc,x1,wsB,lds,s_lds,brow0,tid);
    store_group<512,5>(acc,out,brow0,tid);
  }
}

extern "C" void kernel_launch(void* const* d_in, const int* in_sizes, int n_in,
                              void* d_out, int out_size, void* d_ws, size_t ws_size,
                              hipStream_t stream) {
  const float* x1 = (const float*)d_in[0];
  const float* x2 = (const float*)d_in[1];
  const float* w1 = (const float*)d_in[2];
  const float* w2 = (const float*)d_in[3];
  float* out = (float*)d_out;
  float* wsC = (float*)d_ws;                          // 11*125 floats (CG tensors)
  unsigned char* wsB = (unsigned char*)d_ws + 8192;   // 352 KiB packed bf16 weights
  prep_cg<<<11, 128, 0, stream>>>(wsC);
  prep_w<<<88, 256, 0, stream>>>(w1, w2, wsB);
  tp_main<<<32768/MT, 512, 0, stream>>>(x1, x2, wsC, wsB, out);
}

// Round 12
// 389.707 us; speedup vs baseline: 8.0813x; 1.0491x over previous
//
#include <hip/hip_runtime.h>

typedef float f32x4v __attribute__((ext_vector_type(4)));
typedef short s16x8  __attribute__((ext_vector_type(8)));

#define MT 32  // batch rows per block

constexpr int cI1[11]   = {0,0,0,1,1,1,1,2,2,2,2};
constexpr int cI2[11]   = {0,1,2,0,1,1,2,0,1,2,2};
constexpr int cIO[11]   = {0,1,2,1,0,2,1,2,1,0,2};
constexpr int cSOFF[11] = {0,1,4,9,18,21,36,45,70,85,90};
constexpr int cOFF1[3]  = {0,128,512};
constexpr int cOFF2[3]  = {0,1,4};

__device__ __forceinline__ unsigned short f2bf(float f){
  unsigned int u = __float_as_uint(f);
  u = u + 0x7fffu + ((u>>16)&1u);
  return (unsigned short)(u>>16);
}

// ===================== prep kernel 1: Wigner 3j (parallel, LDS-resident, fp32) =====================
__device__ __forceinline__ float ffact(int n){ float r=1.f; for(int i=2;i<=n;++i) r*=(float)i; return r; }

__device__ float cg1f(int j1,int m1,int j2,int m2,int j3,int m3){
  int vmin = -j1+j2+m3; int t=-j1+m1; if(t>vmin)vmin=t; if(vmin<0)vmin=0;
  int vmax = j2+j3+m1; t=j3-j1+j2; if(t<vmax)vmax=t; t=j3+m3; if(t<vmax)vmax=t;
  float C = sqrtf((2.f*j3+1.f)*ffact(j3+j1-j2)*ffact(j3-j1+j2)*ffact(j1+j2-j3)
                 *ffact(j3+m3)*ffact(j3-m3)
                 /(ffact(j1+j2+j3+1)*ffact(j1-m1)*ffact(j1+m1)*ffact(j2-m2)*ffact(j2+m2)));
  float S=0.f;
  for(int v=vmin;v<=vmax;++v){
    float sg = ((v+j2+m2)&1)? -1.f:1.f;
    S += sg*ffact(j2+j3+m1-v)*ffact(j1-m1+v)
        /(ffact(v)*ffact(j3-j1+j2-v)*ffact(j3+m3-v)*ffact(v+j1-j2-m3));
  }
  return C*S;
}

__global__ void prep_cg(float* __restrict__ wsC){
  __shared__ float s_cg[125];
  __shared__ float s_qr[3][25], s_qi[3][25];
  __shared__ float s_out[125];
  __shared__ float s_inv;
  const int idx = blockIdx.x;
  const int l1=cI1[idx], l2=cI2[idx], l3=cIO[idx];
  const int n1=2*l1+1, n2=2*l2+1, n3=2*l3+1;
  const int tid = threadIdx.x;
  if (tid < 125) s_cg[tid] = 0.f;
  __syncthreads();
  if (tid < 75){
    const int mat=tid/25, e=tid%25, a=e/5, b=e%5;
    const int l = (mat==0)?l1:((mat==1)?l2:l3);
    const int n = 2*l+1;
    float r=0.f, im=0.f;
    if (a<n && b<n){
      const int m = a - l;
      const float s2 = 0.70710678118654752440f;
      if (m < 0){
        if (b == l-m) r = s2;
        else if (b == a) im = -s2;
      } else if (m == 0){
        if (b == a) r = 1.f;
      } else {
        const float sg = (m&1)? -1.f:1.f;
        if (b == a) r = sg*s2;
        else if (b == l-m) im = sg*s2;
      }
      const int ph = l & 3;
      if (ph == 1){ float t=r; r=im; im=-t; }
      else if (ph == 2){ r=-r; im=-im; }
      else if (ph == 3){ float t=r; r=-im; im=t; }
    }
    s_qr[mat][e] = r; s_qi[mat][e] = im;
  }
  if (tid < n1*n2){
    const int m1 = tid / n2 - l1;
    const int m2 = tid % n2 - l2;
    const int m3 = m1 + m2;
    if (m3 >= -l3 && m3 <= l3)
      s_cg[(l1+m1)*25 + (l2+m2)*5 + (l3+m3)] = cg1f(l1,m1,l2,m2,l3,m3);
  }
  __syncthreads();
  const int nElem = n1*n2*n3;
  if (tid < nElem){
    const int j = tid/(n2*n3);
    const int L = (tid/n3) % n2;
    const int m = tid % n3;
    float acc = 0.f;
    for (int i=0;i<n1;i++){
      const float ar=s_qr[0][i*5+j], ai=s_qi[0][i*5+j];
      for (int k=0;k<n2;k++){
        const float br=s_qr[1][k*5+L], bi=s_qi[1][k*5+L];
        const float pr=ar*br-ai*bi, pi=ar*bi+ai*br;
        for (int n=0;n<n3;n++){
          const float c=s_cg[i*25+k*5+n];
          acc += c*(pr*s_qr[2][n*5+m] + pi*s_qi[2][n*5+m]);
        }
      }
    }
    s_out[tid] = acc;
  }
  __syncthreads();
  if (tid == 0){
    float nrm = 0.f;
    for (int t=0;t<nElem;t++) nrm += s_out[t]*s_out[t];
    s_inv = rsqrtf(nrm);
  }
  __syncthreads();
  if (tid < 125){
    const int j=tid/25, L=(tid/5)%5, m=tid%5;
    float v = 0.f;
    if (j<n1 && L<n2 && m<n3) v = s_out[(j*n2+L)*n3+m] * s_inv;
    wsC[idx*125 + tid] = v;
  }
}

// ===================== prep kernel 2: pack W' = w1*w2*pathw as bf16 B-frags =====================
__global__ void prep_w(const float* __restrict__ w1, const float* __restrict__ w2,
                       unsigned char* __restrict__ wsB){
  int gid = blockIdx.x*256 + threadIdx.x;
  if (gid >= 11*8*4*64) return;
  int lane = gid & 63;
  int g = gid >> 6;
  int kst = g & 3, nt = (g>>2)&7, idx = g>>5;
  int io = cIO[idx];
  float pw = (io==0)?0.051031036307982884f:((io==1)?0.07654655446197431f:0.09882117688026186f);
  int u0 = kst*32 + ((lane>>4)&3)*8;
  int w  = nt*16 + (lane&15);
  float w2v = w2[idx*128 + w] * pw;
  s16x8 p;
  #pragma unroll
  for (int e=0;e<8;e++){
    float v = w1[idx*16384 + (u0+e)*128 + w] * w2v;
    p[e] = (short)f2bf(v);
  }
  *(s16x8*)(wsB + (size_t)g*1024 + (size_t)lane*16) = p;
}

// ===================== main kernel: 15-round pipelined =====================
// Round schedule: r0:p0 r1:p4 r2:p9 | r3:p1 r4:p3 r5:p6 r6:p8 | r7:p2a r8:p2b
// r9:p5a r10:p5b r11:p7a r12:p7b r13:p10a r14:p10b  (a: k0-2, b: k3-4)
// Pipeline: round r MFMAs T[r] (built in r-1, buf[r&1]); builds T[r+1] -> buf[(r+1)&1];
// issues xv loads for P(r+2) (skip if same path); issues bfr loads for P(r+1); 1 barrier.

template<int IDX>
__device__ __forceinline__ void xv_load(f32x4v (&xv)[10], const float* __restrict__ x1, int brow0, int tid){
  constexpr int NI = 2*cI1[IDX]+1;
  const int tb = tid>>4, tu0 = (tid&15)*8;
  const float* xrow = x1 + (size_t)(brow0+tb)*1152 + cOFF1[cI1[IDX]] + tu0*NI;
  #pragma unroll
  for(int f=0; f<2*NI; f++) xv[f] = ((const f32x4v*)xrow)[f];
}

template<int IDX>
__device__ __forceinline__ void bfr_load(s16x8 (&bfr)[2][4], const unsigned char* __restrict__ wsB, int tid){
  const int lane=tid&63, wave=tid>>6, ng0=(wave&3)*2;
  #pragma unroll
  for(int nt=0;nt<2;nt++)
    #pragma unroll
    for(int kst=0;kst<4;kst++)
      bfr[nt][kst] = *(const s16x8*)(wsB + (size_t)(((IDX*8+ng0+nt)*4+kst)*64+lane)*16);
}

template<int IDX, int NK, int KB, int NKC>
__device__ __forceinline__ void t_build(const f32x4v (&xv)[10], unsigned char* buf,
                                        const float* s_lds, int tid){
  constexpr int NI = 2*cI1[IDX]+1;
  const int tb = tid>>4, tu0=(tid&15)*8;
  #pragma unroll
  for(int kk=0;kk<NKC;kk++){
    const int k = KB+kk;
    float sv[NI];
    #pragma unroll
    for(int i=0;i<NI;i++) sv[i] = s_lds[tb*116 + cSOFF[IDX] + i*NK + k];
    s16x8 tp;
    #pragma unroll
    for(int u=0;u<8;u++){
      float t=0.f;
      #pragma unroll
      for(int i=0;i<NI;i++){ const int n=u*NI+i; t += sv[i]*xv[n>>2][n&3]; }
      tp[u]=(short)f2bf(t);
    }
    *(s16x8*)(buf + kk*8192 + tb*256 + ((tu0*2) ^ ((tb&7)<<4))) = tp;
  }
}

template<int NACC, int KB, int NKC>
__device__ __forceinline__ void mfma_cons(f32x4v (&acc)[NACC][2], const s16x8 (&bfr)[2][4],
                                          const unsigned char* buf, int tid){
  const int lane=tid&63, wave=tid>>6, mtile=wave>>2;
  const int row = mtile*16 + (lane&15);
  const int rsw = (row&7)<<4, hi=(lane>>4)&3;
  #pragma unroll
  for(int kk=0;kk<NKC;kk++){
    #pragma unroll
    for(int kst=0;kst<4;kst++){
      s16x8 af = *(const s16x8*)(buf + kk*8192 + row*256 + ((kst*64+hi*16)^rsw));
      #pragma unroll
      for(int nt=0;nt<2;nt++)
        acc[KB+kk][nt] = __builtin_amdgcn_mfma_f32_16x16x32_bf16(af, bfr[nt][kst], acc[KB+kk][nt],0,0,0);
    }
  }
}

template<int OO, int NK>
__device__ __forceinline__ void store_group(f32x4v (&acc)[NK][2], float* __restrict__ out, int brow0, int tid){
  const int lane=tid&63, wave=tid>>6;
  const int mtile=wave>>2, ng0=(wave&3)*2;
  const int r0 = brow0 + mtile*16 + ((lane>>4)&3)*4;
  #pragma unroll
  for(int nt=0;nt<2;nt++){
    const int w = (ng0+nt)*16 + (lane&15);
    #pragma unroll
    for(int k=0;k<NK;k++){
      #pragma unroll
      for(int rr=0;rr<4;rr++)
        out[(size_t)(r0+rr)*1152 + OO + w*NK + k] = acc[k][nt][rr];
    }
  }
}

__global__ __launch_bounds__(512) void tp_main(
    const float* __restrict__ x1, const float* __restrict__ x2,
    const float* __restrict__ wsC, const unsigned char* __restrict__ wsB,
    float* __restrict__ out){
  __shared__ __attribute__((aligned(16))) unsigned char lds[49152 + 32*116*4];
  unsigned char* buf0 = lds;
  unsigned char* buf1 = lds + 24576;
  float* s_lds = (float*)(lds + 49152);
  const int tid = threadIdx.x;
  const int brow0 = blockIdx.x * MT;

  // s-table: s[b][(idx,i,k)] = sum_j C_idx[i,j,k] * x2[b, off2+j]
  if (tid < 352){
    const int b = tid & 31, idx = tid >> 5;
    const int i1=cI1[idx], i2=cI2[idx], io=cIO[idx];
    const int ni=2*i1+1, nj=2*i2+1, nk=2*io+1;
    const float* x2r = x2 + (size_t)(brow0+b)*9 + cOFF2[i2];
    const float* C = wsC + idx*125;
    float xv2[5];
    for(int j=0;j<nj;j++) xv2[j]=x2r[j];
    for(int i=0;i<ni;i++)
      for(int k=0;k<nk;k++){
        float s=0.f;
        for(int j=0;j<nj;j++) s += C[i*25+j*5+k]*xv2[j];
        s_lds[b*116 + cSOFF[idx] + i*nk + k] = s;
      }
  }

  f32x4v xv[10];
  s16x8 bfr[2][4];

  // prologue
  xv_load<0>(xv, x1, brow0, tid);
  bfr_load<0>(bfr, wsB, tid);
  __syncthreads();                       // s-table ready
  t_build<0,1,0,1>(xv, buf0, s_lds, tid);
  xv_load<4>(xv, x1, brow0, tid);
  __syncthreads();                       // T[0] ready

  { // io0: rounds 0-2, acc over k=0 only
    f32x4v accA[1][2] = {};
    // r0: mfma p0; build p4; prefetch p9
    mfma_cons<1,0,1>(accA, bfr, buf0, tid);
    t_build<4,1,0,1>(xv, buf1, s_lds, tid);
    xv_load<9>(xv, x1, brow0, tid);
    bfr_load<4>(bfr, wsB, tid);
    __syncthreads();
    // r1: mfma p4; build p9; prefetch p1
    mfma_cons<1,0,1>(accA, bfr, buf1, tid);
    t_build<9,1,0,1>(xv, buf0, s_lds, tid);
    xv_load<1>(xv, x1, brow0, tid);
    bfr_load<9>(bfr, wsB, tid);
    __syncthreads();
    // r2: mfma p9; build p1; prefetch p3
    mfma_cons<1,0,1>(accA, bfr, buf0, tid);
    t_build<1,3,0,3>(xv, buf1, s_lds, tid);
    xv_load<3>(xv, x1, brow0, tid);
    bfr_load<1>(bfr, wsB, tid);
    store_group<0,1>(accA, out, brow0, tid);
    __syncthreads();
  }
  { // io1: rounds 3-6
    f32x4v accB[3][2] = {};
    // r3: mfma p1; build p3; prefetch p6
    mfma_cons<3,0,3>(accB, bfr, buf1, tid);
    t_build<3,3,0,3>(xv, buf0, s_lds, tid);
    xv_load<6>(xv, x1, brow0, tid);
    bfr_load<3>(bfr, wsB, tid);
    __syncthreads();
    // r4: mfma p3; build p6; prefetch p8
    mfma_cons<3,0,3>(accB, bfr, buf0, tid);
    t_build<6,3,0,3>(xv, buf1, s_lds, tid);
    xv_load<8>(xv, x1, brow0, tid);
    bfr_load<6>(bfr, wsB, tid);
    __syncthreads();
    // r5: mfma p6; build p8; prefetch p2
    mfma_cons<3,0,3>(accB, bfr, buf1, tid);
    t_build<8,3,0,3>(xv, buf0, s_lds, tid);
    xv_load<2>(xv, x1, brow0, tid);
    bfr_load<8>(bfr, wsB, tid);
    __syncthreads();
    // r6: mfma p8; build p2a (k0-2); p2b same path -> no xv load
    mfma_cons<3,0,3>(accB, bfr, buf0, tid);
    t_build<2,5,0,3>(xv, buf1, s_lds, tid);
    bfr_load<2>(bfr, wsB, tid);
    store_group<128,3>(accB, out, brow0, tid);
    __syncthreads();
  }
  { // io2: rounds 7-14
    f32x4v accC[5][2] = {};
    // r7: mfma p2a; build p2b (k3-4, same xv); prefetch p5
    mfma_cons<5,0,3>(accC, bfr, buf1, tid);
    t_build<2,5,3,2>(xv, buf0, s_lds, tid);
    xv_load<5>(xv, x1, brow0, tid);
    __syncthreads();
    // r8: mfma p2b; build p5a; p5b same path
    mfma_cons<5,3,2>(accC, bfr, buf0, tid);
    t_build<5,5,0,3>(xv, buf1, s_lds, tid);
    bfr_load<5>(bfr, wsB, tid);
    __syncthreads();
    // r9: mfma p5a; build p5b; prefetch p7
    mfma_cons<5,0,3>(accC, bfr, buf1, tid);
    t_build<5,5,3,2>(xv, buf0, s_lds, tid);
    xv_load<7>(xv, x1, brow0, tid);
    __syncthreads();
    // r10: mfma p5b; build p7a
    mfma_cons<5,3,2>(accC, bfr, buf0, tid);
    t_build<7,5,0,3>(xv, buf1, s_lds, tid);
    bfr_load<7>(bfr, wsB, tid);
    __syncthreads();
    // r11: mfma p7a; build p7b; prefetch p10
    mfma_cons<5,0,3>(accC, bfr, buf1, tid);
    t_build<7,5,3,2>(xv, buf0, s_lds, tid);
    xv_load<10>(xv, x1, brow0, tid);
    __syncthreads();
    // r12: mfma p7b; build p10a
    mfma_cons<5,3,2>(accC, bfr, buf0, tid);
    t_build<10,5,0,3>(xv, buf1, s_lds, tid);
    bfr_load<10>(bfr, wsB, tid);
    __syncthreads();
    // r13: mfma p10a; build p10b
    mfma_cons<5,0,3>(accC, bfr, buf1, tid);
    t_build<10,5,3,2>(xv, buf0, s_lds, tid);
    __syncthreads();
    // r14: mfma p10b; store
    mfma_cons<5,3,2>(accC, bfr, buf0, tid);
    store_group<512,5>(accC, out, brow0, tid);
  }
}

extern "C" void kernel_launch(void* const* d_in, const int* in_sizes, int n_in,
                              void* d_out, int out_size, void* d_ws, size_t ws_size,
                              hipStream_t stream) {
  const float* x1 = (const float*)d_in[0];
  const float* x2 = (const float*)d_in[1];
  const float* w1 = (const float*)d_in[2];
  const float* w2 = (const float*)d_in[3];
  float* out = (float*)d_out;
  float* wsC = (float*)d_ws;                          // 11*125 floats (CG tensors)
  unsigned char* wsB = (unsigned char*)d_ws + 8192;   // 352 KiB packed bf16 weights
  prep_cg<<<11, 128, 0, stream>>>(wsC);
  prep_w<<<88, 256, 0, stream>>>(w1, w2, wsB);
  tp_main<<<32768/MT, 512, 0, stream>>>(x1, x2, wsC, wsB, out);
}